// Round 1
// baseline (284.203 us; speedup 1.0000x reference)
//
#include <hip/hip_runtime.h>
#include <math.h>

#define EMBED 1024
#define NHEAD 16
#define HDIM  64
#define SEQT  2048
#define BATCH 4

typedef __bf16 bf16x4 __attribute__((ext_vector_type(4)));
typedef __bf16 bf16x8 __attribute__((ext_vector_type(8)));
typedef float  f32x4  __attribute__((ext_vector_type(4)));

#define AS1 __attribute__((address_space(1)))
#define AS3 __attribute__((address_space(3)))
// async global->LDS, 16B per lane (guide §5: width=16, m97-verified)
#define GLD_LDS16(gp, lp) __builtin_amdgcn_global_load_lds( \
    (const AS1 unsigned int*)(gp), (AS3 unsigned int*)(lp), 16, 0, 0)

// log2(e) / sqrt(HDIM): folded into Q at QKV-epilogue so scores are exp2-ready
#define QSCALE 0.180336880f

// native cast (v_cvt_pk_bf16_f32 on gfx950)
__device__ __forceinline__ unsigned short f2bf_hw(float f) {
    union { __bf16 h; unsigned short u; } c; c.h = (__bf16)f; return c.u;
}

// one launch converts x, W_qkv, W_proj (fp32 -> bf16), in float4 units
__global__ __launch_bounds__(256)
void cvt_all(const float* __restrict__ x, const float* __restrict__ wq,
             const float* __restrict__ wp,
             unsigned short* __restrict__ xb, unsigned short* __restrict__ wqb,
             unsigned short* __restrict__ wpb)
{
    const int N1 = 2097152;            // 8192*1024/4
    const int N2 = 786432;             // 3*1024*1024/4
    int i = blockIdx.x * 256 + threadIdx.x;
    const float4* src; ushort4* dst; int j;
    if (i < N1)            { src = (const float4*)x;  dst = (ushort4*)xb;  j = i; }
    else if (i < N1 + N2)  { src = (const float4*)wq; dst = (ushort4*)wqb; j = i - N1; }
    else                   { src = (const float4*)wp; dst = (ushort4*)wpb; j = i - N1 - N2; }
    float4 v = src[j];
    ushort4 o;
    o.x = f2bf_hw(v.x); o.y = f2bf_hw(v.y); o.z = f2bf_hw(v.z); o.w = f2bf_hw(v.w);
    dst[j] = o;
}

// ---------------- bf16 MFMA GEMM, 256x256 8-phase schedule (m201 template) ------
// C[m,n] = sum_k A[m,k]*Bw[n,k] + bias[n].  256x256 tile, BK=64, 512 thr (8 waves
// 2Mx4N, per-wave 128x64). LDS double-buffered (128 KiB, 1 block/CU).
// Per K-tile: 4 phases (quadrant Gray order 00->01->11->10, A/B frag reuse:
// 12/4/8/4 ds_read_b128 + 16 MFMA each), raw s_barrier (NO __syncthreads ->
// no implicit vmcnt(0) drain). Tile k+1's 8 global_load_lds issued in phase 0
// of tile k; single vmcnt(0) at the tile boundary waits on loads ~4 phases old.
// T2: LDS 16B-slot XOR swizzle (slot ^= row&7) on reads; inverse swizzle
// pre-applied to the per-lane GLOBAL source (rule #21: gld_lds writes linearly).
#define BAR do { __builtin_amdgcn_sched_barrier(0); \
                 __builtin_amdgcn_s_barrier(); \
                 __builtin_amdgcn_sched_barrier(0); } while (0)

template<int MODE>
__global__ __launch_bounds__(512, 2)
void gemm_bt_8ph(const unsigned short* __restrict__ A, const unsigned short* __restrict__ Bw,
                 const float* __restrict__ bias,
                 void* out0, void* out1, void* out2,
                 int M, int N, int K)
{
    __shared__ __align__(16) unsigned short Asm[2][256 * 64];   // 2 x 32 KB
    __shared__ __align__(16) unsigned short Bsm[2][256 * 64];   // 2 x 32 KB

    const int tid  = threadIdx.x;
    const int lane = tid & 63;
    const int wave = tid >> 6;
    const int wm = wave >> 2, wn = wave & 3;          // 2 x 4 wave grid
    const int col = lane & 15, quad = lane >> 4;
    const long m0 = (long)blockIdx.y * 256, n0 = (long)blockIdx.x * 256;

    f32x4 acc[8][4];
#pragma unroll
    for (int mi = 0; mi < 8; mi++)
#pragma unroll
        for (int ni = 0; ni < 4; ni++) acc[mi][ni] = (f32x4){0.f, 0.f, 0.f, 0.f};

    // staging geometry: round r covers rows r*64 + (tid>>3); 16B slot (tid&7).
    // LDS dest is linear (base + tid*16B); source column-slot pre-swizzled.
    const int srow  = tid >> 3;                // 0..63
    const int sslot = tid & 7;
    const int gslot = sslot ^ (srow & 7);      // inverse of the read-side XOR
    const unsigned short* Agb = A  + (m0 + srow) * (long)K + gslot * 8;
    const unsigned short* Bgb = Bw + (n0 + srow) * (long)K + gslot * 8;

#define STAGE(b, kt_) do { const long ko_ = (long)(kt_) * 64; \
    _Pragma("unroll") for (int r_ = 0; r_ < 4; r_++) { \
        GLD_LDS16(Agb + (long)r_ * 64 * K + ko_, &Asm[b][0] + r_ * 4096 + tid * 8); \
        GLD_LDS16(Bgb + (long)r_ * 64 * K + ko_, &Bsm[b][0] + r_ * 4096 + tid * 8); \
    } } while (0)

    // swizzled fragment reads: row stride 64 shorts (128B = 8 x 16B slots);
    // physical slot = logical slot XOR (row&7) -> quad's 16 lanes hit 8 distinct
    // bank groups (2-way = free, guide G4/m136) instead of 16-way.
#define LOAD_A(qm_) do { _Pragma("unroll") for (int i_ = 0; i_ < 4; i_++) { \
        const int row_ = wm * 128 + ((qm_) * 4 + i_) * 16 + col; \
        const int rx_ = row_ & 7; \
        af[i_][0] = *(const bf16x8*)&Ac[row_ * 64 + ((quad    ) ^ rx_) * 8]; \
        af[i_][1] = *(const bf16x8*)&Ac[row_ * 64 + ((quad + 4) ^ rx_) * 8]; \
    } } while (0)

#define LOAD_B(qn_) do { _Pragma("unroll") for (int j_ = 0; j_ < 2; j_++) { \
        const int row_ = wn * 64 + ((qn_) * 2 + j_) * 16 + col; \
        const int rx_ = row_ & 7; \
        bfv[j_][0] = *(const bf16x8*)&Bc[row_ * 64 + ((quad    ) ^ rx_) * 8]; \
        bfv[j_][1] = *(const bf16x8*)&Bc[row_ * 64 + ((quad + 4) ^ rx_) * 8]; \
    } } while (0)

#define MFMA_Q(qm_, qn_) do { __builtin_amdgcn_s_setprio(1); \
    _Pragma("unroll") for (int i_ = 0; i_ < 4; i_++) \
    _Pragma("unroll") for (int j_ = 0; j_ < 2; j_++) { \
        acc[(qm_) * 4 + i_][(qn_) * 2 + j_] = __builtin_amdgcn_mfma_f32_16x16x32_bf16( \
            af[i_][0], bfv[j_][0], acc[(qm_) * 4 + i_][(qn_) * 2 + j_], 0, 0, 0); \
        acc[(qm_) * 4 + i_][(qn_) * 2 + j_] = __builtin_amdgcn_mfma_f32_16x16x32_bf16( \
            af[i_][1], bfv[j_][1], acc[(qm_) * 4 + i_][(qn_) * 2 + j_], 0, 0, 0); \
    } \
    __builtin_amdgcn_s_setprio(0); } while (0)

    // prologue: tile 0 staged + landed
    STAGE(0, 0);
    __builtin_amdgcn_s_waitcnt(0x0F70);   // vmcnt(0)
    BAR;

    const int T = K >> 6;                 // 16 K-tiles
    for (int kt = 0; kt < T; kt++) {
        const int cur = kt & 1;
        const unsigned short* Ac = &Asm[cur][0];
        const unsigned short* Bc = &Bsm[cur][0];
        bf16x8 af[4][2], bfv[2][2];

        // phase 0: quadrant (0,0); issue ALL next-tile staging (stays in
        // flight across the next 7 barriers — T4 counted-vmcnt mechanism)
        LOAD_A(0); LOAD_B(0);
        if (kt + 1 < T) STAGE(cur ^ 1, kt + 1);
        BAR;
        MFMA_Q(0, 0);
        BAR;
        // phase 1: quadrant (0,1) — reuse A, reload B (4 reads)
        LOAD_B(1);
        BAR;
        MFMA_Q(0, 1);
        BAR;
        // phase 2: quadrant (1,1) — reuse B, reload A (8 reads)
        LOAD_A(1);
        BAR;
        MFMA_Q(1, 1);
        BAR;
        // phase 3: quadrant (1,0) — reuse A, reload B (4 reads)
        LOAD_B(0);
        BAR;
        MFMA_Q(1, 0);
        // tile boundary: the ONLY vmcnt wait per K-tile; loads are ~4 phases old
        __builtin_amdgcn_s_waitcnt(0x0F70);
        BAR;
    }

#undef STAGE
#undef LOAD_A
#undef LOAD_B
#undef MFMA_Q

    // epilogue: C/D layout col=lane&15, row=quad*4+r (m89/m91-verified)
#pragma unroll
    for (int mi = 0; mi < 8; mi++) {
#pragma unroll
        for (int ni = 0; ni < 4; ni++) {
            long n = n0 + wn * 64 + ni * 16 + col;
            float bv = bias[n];
#pragma unroll
            for (int r = 0; r < 4; r++) {
                long m = m0 + wm * 128 + mi * 16 + quad * 4 + r;
                float v = acc[mi][ni][r] + bv;
                if (MODE == 0) {
                    ((float*)out0)[m * N + n] = v;
                } else {
                    int which = (int)(n >> 10);
                    int c = (int)(n & 1023);
                    int h = c >> 6, d = c & 63;
                    int b = (int)(m >> 11), t = (int)(m & 2047);
                    long bh = (long)(b * NHEAD + h);
                    if (which == 0)      ((unsigned short*)out0)[(bh * SEQT + t) * HDIM + d] = f2bf_hw(v * QSCALE);
                    else if (which == 1) ((unsigned short*)out1)[(bh * SEQT + t) * HDIM + d] = f2bf_hw(v);
                    else                 ((unsigned short*)out2)[(bh * HDIM + d) * SEQT + t] = f2bf_hw(v);
                }
            }
        }
    }
}

// ---------------- bf16 MFMA flash attention, v4 (unchanged) ----------------
// Q-tile 128; 4 waves × 32 q-rows. No-max softmax; S computed transposed
// (mfma(K,Q)) -> packed b64 P stores; P stored [q][k] for b128 PV A-frag reads.
#define PPAD 72

__global__ __launch_bounds__(256, 3)
void flash_attn_mfma4(const unsigned short* __restrict__ Qb,
                      const unsigned short* __restrict__ Kb,
                      const unsigned short* __restrict__ Vt,
                      unsigned short* __restrict__ Ob)
{
    __shared__ __align__(16) unsigned short P_lds[128 * PPAD];    // [q][k] 18432 B
    __shared__ __align__(16) unsigned short K_lds[2][64 * 64];    // 16 KB
    __shared__ __align__(16) unsigned short V_lds[2][64 * 64];    // 16 KB
    __shared__ __align__(16) float L_lds[128];                    // row sums

    const int tid  = threadIdx.x;
    const int lane = tid & 63;
    const int wave = tid >> 6;
    const int col  = lane & 15;
    const int quad = lane >> 4;

    const int idx = blockIdx.x;
    const int qt = 15 - (idx >> 6);      // longest blocks dispatched first
    const int hb = idx & 63;
    const int h = hb & 15, b = hb >> 4;
    const int q0 = qt * 128;
    const long bh = (long)(b * NHEAD + h);
    const unsigned short* Kbh = Kb + bh * SEQT * HDIM;
    const unsigned short* Vbh = Vt + bh * HDIM * SEQT;
    const int ktiles = 2 * qt + 2;

    const int r0 = tid >> 3,         c0 = (tid & 7) ^ (r0 & 7);
    const int r1 = (tid + 256) >> 3, c1 = (tid & 7) ^ (r1 & 7);

    bf16x8 qf[2][2];
#pragma unroll
    for (int ni = 0; ni < 2; ni++) {
        const unsigned short* qrow = Qb + (bh * SEQT + q0 + wave * 32 + ni * 16 + col) * HDIM;
        qf[ni][0] = *(const bf16x8*)(qrow + quad * 8);
        qf[ni][1] = *(const bf16x8*)(qrow + 32 + quad * 8);
    }

    GLD_LDS16(Kbh + r0 * HDIM + c0 * 8,        &K_lds[0][0] + tid * 8);
    GLD_LDS16(Kbh + r1 * HDIM + c1 * 8,        &K_lds[0][0] + 2048 + tid * 8);
    GLD_LDS16(Vbh + (long)r0 * SEQT + c0 * 8,  &V_lds[0][0] + tid * 8);
    GLD_LDS16(Vbh + (long)r1 * SEQT + c1 * 8,  &V_lds[0][0] + 2048 + tid * 8);

    f32x4 o[2][4];
#pragma unroll
    for (int mi = 0; mi < 2; mi++)
#pragma unroll
        for (int dt = 0; dt < 4; dt++) o[mi][dt] = (f32x4){0.f, 0.f, 0.f, 0.f};
    float rs[2] = {0.f, 0.f};

    const int cswz0 = quad ^ (col & 7);
    const int cswz1 = (quad + 4) ^ (col & 7);

    for (int kt = 0; kt < ktiles; kt++) {
        const int cur = kt & 1;
        __builtin_amdgcn_s_waitcnt(0x0F70);   // vmcnt(0)
        __syncthreads();
        if (kt + 1 < ktiles) {
            const int k0n = (kt + 1) * 64, nxt = cur ^ 1;
            GLD_LDS16(Kbh + (k0n + r0) * HDIM + c0 * 8,       &K_lds[nxt][0] + tid * 8);
            GLD_LDS16(Kbh + (k0n + r1) * HDIM + c1 * 8,       &K_lds[nxt][0] + 2048 + tid * 8);
            GLD_LDS16(Vbh + (long)r0 * SEQT + k0n + c0 * 8,   &V_lds[nxt][0] + tid * 8);
            GLD_LDS16(Vbh + (long)r1 * SEQT + k0n + c1 * 8,   &V_lds[nxt][0] + 2048 + tid * 8);
        }

        // S^T = K Q^T : A = K (m=key), B = Q (n=query). C: col=q, row=key.
        const unsigned short* Kc = &K_lds[cur][0];
        f32x4 st[4][2];
#pragma unroll
        for (int mt = 0; mt < 4; mt++) {
            const int row = mt * 16 + col;
            bf16x8 kf0 = *(const bf16x8*)&Kc[row * 64 + cswz0 * 8];
            bf16x8 kf1 = *(const bf16x8*)&Kc[row * 64 + cswz1 * 8];
#pragma unroll
            for (int ni = 0; ni < 2; ni++) {
                f32x4 acc = (f32x4){0.f, 0.f, 0.f, 0.f};
                acc = __builtin_amdgcn_mfma_f32_16x16x32_bf16(kf0, qf[ni][0], acc, 0, 0, 0);
                acc = __builtin_amdgcn_mfma_f32_16x16x32_bf16(kf1, qf[ni][1], acc, 0, 0, 0);
                st[mt][ni] = acc;
            }
        }
        const int k0 = kt * 64;
        if (kt >= 2 * qt) {                // diagonal tiles: mask key > q
#pragma unroll
            for (int mt = 0; mt < 4; mt++) {
                const int keybase = k0 + mt * 16 + quad * 4;
#pragma unroll
                for (int ni = 0; ni < 2; ni++) {
                    const int qg = q0 + wave * 32 + ni * 16 + col;
#pragma unroll
                    for (int r = 0; r < 4; r++)
                        if (keybase + r > qg) st[mt][ni][r] = -INFINITY;
                }
            }
        }

        // p = exp2(s); accumulate row-sum partials; packed b64 P-store
#pragma unroll
        for (int mt = 0; mt < 4; mt++)
#pragma unroll
            for (int ni = 0; ni < 2; ni++) {
                f32x4 p;
#pragma unroll
                for (int r = 0; r < 4; r++) p[r] = __builtin_amdgcn_exp2f(st[mt][ni][r]);
                rs[ni] += (p[0] + p[1]) + (p[2] + p[3]);
                bf16x4 pb = __builtin_convertvector(p, bf16x4);
                *(bf16x4*)&P_lds[(wave * 32 + ni * 16 + col) * PPAD + mt * 16 + quad * 4] = pb;
            }

        // PV: A = P[q][k] (wave-private rows), B = V^T
        const unsigned short* Vc = &V_lds[cur][0];
#pragma unroll
        for (int mi = 0; mi < 2; mi++) {
            const unsigned short* prow = &P_lds[(wave * 32 + mi * 16 + col) * PPAD];
            bf16x8 pf0 = *(const bf16x8*)(prow + quad * 8);
            bf16x8 pf1 = *(const bf16x8*)(prow + 32 + quad * 8);
#pragma unroll
            for (int dt = 0; dt < 4; dt++) {
                const int row = dt * 16 + col;
                bf16x8 vf0 = *(const bf16x8*)&Vc[row * 64 + cswz0 * 8];
                bf16x8 vf1 = *(const bf16x8*)&Vc[row * 64 + cswz1 * 8];
                o[mi][dt] = __builtin_amdgcn_mfma_f32_16x16x32_bf16(pf0, vf0, o[mi][dt], 0, 0, 0);
                o[mi][dt] = __builtin_amdgcn_mfma_f32_16x16x32_bf16(pf1, vf1, o[mi][dt], 0, 0, 0);
            }
        }
    }

    // final row-sum reduction over quads (partials partitioned by quad)
#pragma unroll
    for (int ni = 0; ni < 2; ni++) {
        rs[ni] += __shfl_xor(rs[ni], 16);
        rs[ni] += __shfl_xor(rs[ni], 32);
        if (quad == 0) L_lds[wave * 32 + ni * 16 + col] = rs[ni];
    }
    __syncthreads();
    f32x4 lf[2];
#pragma unroll
    for (int mi = 0; mi < 2; mi++)
        lf[mi] = *(const f32x4*)&L_lds[wave * 32 + mi * 16 + quad * 4];

    // epilogue: bf16 Ob[b][t][h*64+d]
#pragma unroll
    for (int mi = 0; mi < 2; mi++)
#pragma unroll
        for (int r = 0; r < 4; r++) {
            float inv = 1.f / lf[mi][r];
            int t = q0 + wave * 32 + mi * 16 + quad * 4 + r;
            unsigned short* orow = Ob + ((long)(b * SEQT + t)) * EMBED + h * HDIM;
#pragma unroll
            for (int dt = 0; dt < 4; dt++)
                orow[dt * 16 + col] = f2bf_hw(o[mi][dt][r] * inv);
        }
}

extern "C" void kernel_launch(void* const* d_in, const int* in_sizes, int n_in,
                              void* d_out, int out_size, void* d_ws, size_t ws_size,
                              hipStream_t stream)
{
    const float* x     = (const float*)d_in[0];
    const float* Wqkv  = (const float*)d_in[1];
    const float* bqkv  = (const float*)d_in[2];
    const float* Wproj = (const float*)d_in[3];
    const float* bproj = (const float*)d_in[4];
    float* out = (float*)d_out;

    const long Mbt = (long)BATCH * SEQT;                 // 8192
    const long per = (long)BATCH * NHEAD * SEQT * HDIM;  // 8,388,608 elems

    unsigned short* xb  = (unsigned short*)d_ws;
    unsigned short* wqb = xb  + per;
    unsigned short* wpb = wqb + 3 * EMBED * EMBED;
    unsigned short* Qb  = wpb + EMBED * EMBED;           // bf16 [bh][t][d], pre-scaled
    unsigned short* Kb  = Qb + per;
    unsigned short* Vt  = Kb + per;                      // bf16 [bh][d][t]
    unsigned short* Ob  = Vt + per;                      // bf16 [B,T,C]

    cvt_all<<<12288, 256, 0, stream>>>(x, Wqkv, Wproj, xb, wqb, wpb);

    dim3 g1(3 * EMBED / 256, Mbt / 256);
    gemm_bt_8ph<1><<<g1, 512, 0, stream>>>(xb, wqb, bqkv, Qb, Kb, Vt,
                                           (int)Mbt, 3 * EMBED, EMBED);

    flash_attn_mfma4<<<1024, 256, 0, stream>>>(Qb, Kb, Vt, Ob);

    dim3 g3(EMBED / 256, Mbt / 256);
    gemm_bt_8ph<0><<<g3, 512, 0, stream>>>(Ob, wpb, bproj, out, nullptr, nullptr,
                                           (int)Mbt, EMBED, EMBED);
}

// Round 2
// 253.247 us; speedup vs baseline: 1.1222x; 1.1222x over previous
//
#include <hip/hip_runtime.h>
#include <math.h>

#define EMBED 1024
#define NHEAD 16
#define HDIM  64
#define SEQT  2048
#define BATCH 4

typedef __bf16 bf16x4 __attribute__((ext_vector_type(4)));
typedef __bf16 bf16x8 __attribute__((ext_vector_type(8)));
typedef float  f32x4  __attribute__((ext_vector_type(4)));

#define AS1 __attribute__((address_space(1)))
#define AS3 __attribute__((address_space(3)))
// async global->LDS, 16B per lane (guide §5: width=16, m97-verified)
#define GLD_LDS16(gp, lp) __builtin_amdgcn_global_load_lds( \
    (const AS1 unsigned int*)(gp), (AS3 unsigned int*)(lp), 16, 0, 0)

// log2(e) / sqrt(HDIM): folded into Q at QKV-epilogue so scores are exp2-ready
#define QSCALE 0.180336880f

// native cast (v_cvt_pk_bf16_f32 on gfx950)
__device__ __forceinline__ unsigned short f2bf_hw(float f) {
    union { __bf16 h; unsigned short u; } c; c.h = (__bf16)f; return c.u;
}

// one launch converts x, W_qkv, W_proj (fp32 -> bf16), in float4 units
__global__ __launch_bounds__(256)
void cvt_all(const float* __restrict__ x, const float* __restrict__ wq,
             const float* __restrict__ wp,
             unsigned short* __restrict__ xb, unsigned short* __restrict__ wqb,
             unsigned short* __restrict__ wpb)
{
    const int N1 = 2097152;            // 8192*1024/4
    const int N2 = 786432;             // 3*1024*1024/4
    int i = blockIdx.x * 256 + threadIdx.x;
    const float4* src; ushort4* dst; int j;
    if (i < N1)            { src = (const float4*)x;  dst = (ushort4*)xb;  j = i; }
    else if (i < N1 + N2)  { src = (const float4*)wq; dst = (ushort4*)wqb; j = i - N1; }
    else                   { src = (const float4*)wp; dst = (ushort4*)wpb; j = i - N1 - N2; }
    float4 v = src[j];
    ushort4 o;
    o.x = f2bf_hw(v.x); o.y = f2bf_hw(v.y); o.z = f2bf_hw(v.z); o.w = f2bf_hw(v.w);
    dst[j] = o;
}

// ---------------- bf16 MFMA GEMM, 256x128 / BK=64 / 3-buffer pipeline ----------
// C[m,n] = sum_k A[m,k]*Bw[n,k] + bias[n].  512 thr = 8 waves (4M x 2N), per-wave
// 64x64 output (acc 4x4 of 16x16x32 — R0-verified fragment geometry).
// LDS: 3 buffers x (A 32KB + B 16KB) = 144 KiB -> 1 block/CU.
// Pipeline (T3+T4): tile t+2's 6 global_load_lds issued during tile t (A 4 loads
// in phase 0, B 2 loads in phase 1); end-of-tile wait is vmcnt(6) = "all but the
// newest 6 landed" -> tile t+1 guaranteed resident, tile t+2 stays IN FLIGHT
// across the barrier (counted wait, never 0 in steady state — m218 mechanism).
// Issue->wait distance ~2 tiles (~4 MFMA phases). WAR: buf[(t+2)%3] was last
// read in tile t-1, strictly before the barrier preceding the stage issue.
// T2: LDS 16B-slot XOR swizzle (slot ^= row&7) on reads; inverse pre-applied to
// the per-lane GLOBAL source (rule #21; R1-verified: bank conflicts -> 0).
#define BAR do { __builtin_amdgcn_sched_barrier(0); \
                 __builtin_amdgcn_s_barrier(); \
                 __builtin_amdgcn_sched_barrier(0); } while (0)

template<int MODE>
__global__ __launch_bounds__(512, 2)
void gemm_bt_pipe(const unsigned short* __restrict__ A, const unsigned short* __restrict__ Bw,
                  const float* __restrict__ bias,
                  void* out0, void* out1, void* out2,
                  int M, int N)
{
    const int K = 1024;                 // both GEMMs have K=1024
    const int T = 16;                   // K / 64
    __shared__ __align__(16) unsigned short Asm[3][256 * 64];   // 3 x 32 KB
    __shared__ __align__(16) unsigned short Bsm[3][128 * 64];   // 3 x 16 KB

    const int tid  = threadIdx.x;
    const int lane = tid & 63;
    const int wave = tid >> 6;
    const int wm = wave >> 1, wn = wave & 1;          // 4M x 2N wave grid
    const int col = lane & 15, quad = lane >> 4;

    // T1: XCD chunk swizzle on the linear block id (nwg % 8 == 0 for both grids)
    const int gx = gridDim.x;
    const int nwg = gx * gridDim.y;
    int wg = blockIdx.y * gx + blockIdx.x;
    wg = (wg & 7) * (nwg >> 3) + (wg >> 3);
    const long m0 = (long)(wg / gx) * 256;
    const long n0 = (long)(wg % gx) * 128;

    f32x4 acc[4][4];
#pragma unroll
    for (int mi = 0; mi < 4; mi++)
#pragma unroll
        for (int ni = 0; ni < 4; ni++) acc[mi][ni] = (f32x4){0.f, 0.f, 0.f, 0.f};

    // staging geometry: thread covers row (tid>>3) of each 64-row group, 16B slot
    // (tid&7). LDS dest linear (tid*16B); source slot pre-swizzled (^ row&7).
    const int srow  = tid >> 3;                // 0..63
    const int sslot = tid & 7;
    const int gslot = sslot ^ (srow & 7);
    const unsigned short* Agb = A  + (m0 + srow) * (long)K + gslot * 8;
    const unsigned short* Bgb = Bw + (n0 + srow) * (long)K + gslot * 8;

#define STAGE_A(b, t_) do { const long ko_ = (long)(t_) * 64; \
    _Pragma("unroll") for (int r_ = 0; r_ < 4; r_++) \
        GLD_LDS16(Agb + (long)r_ * 64 * K + ko_, &Asm[b][0] + r_ * 4096 + tid * 8); \
    } while (0)
#define STAGE_B(b, t_) do { const long ko_ = (long)(t_) * 64; \
    _Pragma("unroll") for (int r_ = 0; r_ < 2; r_++) \
        GLD_LDS16(Bgb + (long)r_ * 64 * K + ko_, &Bsm[b][0] + r_ * 4096 + tid * 8); \
    } while (0)

    // swizzled fragment reads: row stride 64 shorts (128B = 8 slots); physical
    // slot = (ks*4+quad) ^ (row&7) -> wave hits 32 banks with exactly 2 lanes
    // each (free; R1 measured SQ_LDS_BANK_CONFLICT = 0).
#define LOAD_A() do { _Pragma("unroll") for (int i_ = 0; i_ < 4; i_++) { \
        const int row_ = wm * 64 + i_ * 16 + col; \
        const int rx_ = row_ & 7; \
        af[i_][0] = *(const bf16x8*)&Ac[row_ * 64 + ((quad    ) ^ rx_) * 8]; \
        af[i_][1] = *(const bf16x8*)&Ac[row_ * 64 + ((quad + 4) ^ rx_) * 8]; \
    } } while (0)

#define LOAD_B(qn_) do { _Pragma("unroll") for (int j_ = 0; j_ < 2; j_++) { \
        const int row_ = wn * 64 + (qn_) * 32 + j_ * 16 + col; \
        const int rx_ = row_ & 7; \
        bfv[j_][0] = *(const bf16x8*)&Bc[row_ * 64 + ((quad    ) ^ rx_) * 8]; \
        bfv[j_][1] = *(const bf16x8*)&Bc[row_ * 64 + ((quad + 4) ^ rx_) * 8]; \
    } } while (0)

#define MFMA_Q(qn_) do { __builtin_amdgcn_s_setprio(1); \
    _Pragma("unroll") for (int i_ = 0; i_ < 4; i_++) \
    _Pragma("unroll") for (int j_ = 0; j_ < 2; j_++) { \
        acc[i_][(qn_) * 2 + j_] = __builtin_amdgcn_mfma_f32_16x16x32_bf16( \
            af[i_][0], bfv[j_][0], acc[i_][(qn_) * 2 + j_], 0, 0, 0); \
        acc[i_][(qn_) * 2 + j_] = __builtin_amdgcn_mfma_f32_16x16x32_bf16( \
            af[i_][1], bfv[j_][1], acc[i_][(qn_) * 2 + j_], 0, 0, 0); \
    } \
    __builtin_amdgcn_s_setprio(0); } while (0)

    // prologue: tiles 0,1 staged; wait tile 0 only (tile 1's 6 stay in flight)
    STAGE_A(0, 0); STAGE_B(0, 0);
    STAGE_A(1, 1); STAGE_B(1, 1);
    __builtin_amdgcn_s_waitcnt(0x0F76);   // vmcnt(6)
    BAR;

#pragma unroll
    for (int t = 0; t < T; t++) {
        const int cur = t % 3, nb = (t + 2) % 3;
        const unsigned short* Ac = &Asm[cur][0];
        const unsigned short* Bc = &Bsm[cur][0];
        bf16x8 af[4][2], bfv[2][2];

        // phase 0: A-frags (8 ds_read_b128) + B half 0 (4); issue tile t+2's A
        LOAD_A(); LOAD_B(0);
        if (t + 2 < T) STAGE_A(nb, t + 2);
        BAR;
        MFMA_Q(0);
        BAR;
        // phase 1: B half 1 (4 ds_read_b128); issue tile t+2's B
        LOAD_B(1);
        if (t + 2 < T) STAGE_B(nb, t + 2);
        BAR;
        MFMA_Q(1);
        // tile boundary: counted wait — tile t+1 resident, tile t+2 in flight
        if (t + 2 < T)       __builtin_amdgcn_s_waitcnt(0x0F76);  // vmcnt(6)
        else if (t + 2 == T) __builtin_amdgcn_s_waitcnt(0x0F70);  // vmcnt(0)
        BAR;
    }

#undef STAGE_A
#undef STAGE_B
#undef LOAD_A
#undef LOAD_B
#undef MFMA_Q

    // epilogue: C/D layout col=lane&15, row=quad*4+r (m89/m91-verified)
#pragma unroll
    for (int mi = 0; mi < 4; mi++) {
#pragma unroll
        for (int ni = 0; ni < 4; ni++) {
            long n = n0 + wn * 64 + ni * 16 + col;
            float bv = bias[n];
#pragma unroll
            for (int r = 0; r < 4; r++) {
                long m = m0 + wm * 64 + mi * 16 + quad * 4 + r;
                float v = acc[mi][ni][r] + bv;
                if (MODE == 0) {
                    ((float*)out0)[m * N + n] = v;
                } else {
                    int which = (int)(n >> 10);
                    int c = (int)(n & 1023);
                    int h = c >> 6, d = c & 63;
                    int b = (int)(m >> 11), t = (int)(m & 2047);
                    long bh = (long)(b * NHEAD + h);
                    if (which == 0)      ((unsigned short*)out0)[(bh * SEQT + t) * HDIM + d] = f2bf_hw(v * QSCALE);
                    else if (which == 1) ((unsigned short*)out1)[(bh * SEQT + t) * HDIM + d] = f2bf_hw(v);
                    else                 ((unsigned short*)out2)[(bh * HDIM + d) * SEQT + t] = f2bf_hw(v);
                }
            }
        }
    }
}

// ---------------- bf16 MFMA flash attention, v4 (unchanged) ----------------
// Q-tile 128; 4 waves × 32 q-rows. No-max softmax; S computed transposed
// (mfma(K,Q)) -> packed b64 P stores; P stored [q][k] for b128 PV A-frag reads.
#define PPAD 72

__global__ __launch_bounds__(256, 3)
void flash_attn_mfma4(const unsigned short* __restrict__ Qb,
                      const unsigned short* __restrict__ Kb,
                      const unsigned short* __restrict__ Vt,
                      unsigned short* __restrict__ Ob)
{
    __shared__ __align__(16) unsigned short P_lds[128 * PPAD];    // [q][k] 18432 B
    __shared__ __align__(16) unsigned short K_lds[2][64 * 64];    // 16 KB
    __shared__ __align__(16) unsigned short V_lds[2][64 * 64];    // 16 KB
    __shared__ __align__(16) float L_lds[128];                    // row sums

    const int tid  = threadIdx.x;
    const int lane = tid & 63;
    const int wave = tid >> 6;
    const int col  = lane & 15;
    const int quad = lane >> 4;

    const int idx = blockIdx.x;
    const int qt = 15 - (idx >> 6);      // longest blocks dispatched first
    const int hb = idx & 63;
    const int h = hb & 15, b = hb >> 4;
    const int q0 = qt * 128;
    const long bh = (long)(b * NHEAD + h);
    const unsigned short* Kbh = Kb + bh * SEQT * HDIM;
    const unsigned short* Vbh = Vt + bh * HDIM * SEQT;
    const int ktiles = 2 * qt + 2;

    const int r0 = tid >> 3,         c0 = (tid & 7) ^ (r0 & 7);
    const int r1 = (tid + 256) >> 3, c1 = (tid & 7) ^ (r1 & 7);

    bf16x8 qf[2][2];
#pragma unroll
    for (int ni = 0; ni < 2; ni++) {
        const unsigned short* qrow = Qb + (bh * SEQT + q0 + wave * 32 + ni * 16 + col) * HDIM;
        qf[ni][0] = *(const bf16x8*)(qrow + quad * 8);
        qf[ni][1] = *(const bf16x8*)(qrow + 32 + quad * 8);
    }

    GLD_LDS16(Kbh + r0 * HDIM + c0 * 8,        &K_lds[0][0] + tid * 8);
    GLD_LDS16(Kbh + r1 * HDIM + c1 * 8,        &K_lds[0][0] + 2048 + tid * 8);
    GLD_LDS16(Vbh + (long)r0 * SEQT + c0 * 8,  &V_lds[0][0] + tid * 8);
    GLD_LDS16(Vbh + (long)r1 * SEQT + c1 * 8,  &V_lds[0][0] + 2048 + tid * 8);

    f32x4 o[2][4];
#pragma unroll
    for (int mi = 0; mi < 2; mi++)
#pragma unroll
        for (int dt = 0; dt < 4; dt++) o[mi][dt] = (f32x4){0.f, 0.f, 0.f, 0.f};
    float rs[2] = {0.f, 0.f};

    const int cswz0 = quad ^ (col & 7);
    const int cswz1 = (quad + 4) ^ (col & 7);

    for (int kt = 0; kt < ktiles; kt++) {
        const int cur = kt & 1;
        __builtin_amdgcn_s_waitcnt(0x0F70);   // vmcnt(0)
        __syncthreads();
        if (kt + 1 < ktiles) {
            const int k0n = (kt + 1) * 64, nxt = cur ^ 1;
            GLD_LDS16(Kbh + (k0n + r0) * HDIM + c0 * 8,       &K_lds[nxt][0] + tid * 8);
            GLD_LDS16(Kbh + (k0n + r1) * HDIM + c1 * 8,       &K_lds[nxt][0] + 2048 + tid * 8);
            GLD_LDS16(Vbh + (long)r0 * SEQT + k0n + c0 * 8,   &V_lds[nxt][0] + tid * 8);
            GLD_LDS16(Vbh + (long)r1 * SEQT + k0n + c1 * 8,   &V_lds[nxt][0] + 2048 + tid * 8);
        }

        // S^T = K Q^T : A = K (m=key), B = Q (n=query). C: col=q, row=key.
        const unsigned short* Kc = &K_lds[cur][0];
        f32x4 st[4][2];
#pragma unroll
        for (int mt = 0; mt < 4; mt++) {
            const int row = mt * 16 + col;
            bf16x8 kf0 = *(const bf16x8*)&Kc[row * 64 + cswz0 * 8];
            bf16x8 kf1 = *(const bf16x8*)&Kc[row * 64 + cswz1 * 8];
#pragma unroll
            for (int ni = 0; ni < 2; ni++) {
                f32x4 acc = (f32x4){0.f, 0.f, 0.f, 0.f};
                acc = __builtin_amdgcn_mfma_f32_16x16x32_bf16(kf0, qf[ni][0], acc, 0, 0, 0);
                acc = __builtin_amdgcn_mfma_f32_16x16x32_bf16(kf1, qf[ni][1], acc, 0, 0, 0);
                st[mt][ni] = acc;
            }
        }
        const int k0 = kt * 64;
        if (kt >= 2 * qt) {                // diagonal tiles: mask key > q
#pragma unroll
            for (int mt = 0; mt < 4; mt++) {
                const int keybase = k0 + mt * 16 + quad * 4;
#pragma unroll
                for (int ni = 0; ni < 2; ni++) {
                    const int qg = q0 + wave * 32 + ni * 16 + col;
#pragma unroll
                    for (int r = 0; r < 4; r++)
                        if (keybase + r > qg) st[mt][ni][r] = -INFINITY;
                }
            }
        }

        // p = exp2(s); accumulate row-sum partials; packed b64 P-store
#pragma unroll
        for (int mt = 0; mt < 4; mt++)
#pragma unroll
            for (int ni = 0; ni < 2; ni++) {
                f32x4 p;
#pragma unroll
                for (int r = 0; r < 4; r++) p[r] = __builtin_amdgcn_exp2f(st[mt][ni][r]);
                rs[ni] += (p[0] + p[1]) + (p[2] + p[3]);
                bf16x4 pb = __builtin_convertvector(p, bf16x4);
                *(bf16x4*)&P_lds[(wave * 32 + ni * 16 + col) * PPAD + mt * 16 + quad * 4] = pb;
            }

        // PV: A = P[q][k] (wave-private rows), B = V^T
        const unsigned short* Vc = &V_lds[cur][0];
#pragma unroll
        for (int mi = 0; mi < 2; mi++) {
            const unsigned short* prow = &P_lds[(wave * 32 + mi * 16 + col) * PPAD];
            bf16x8 pf0 = *(const bf16x8*)(prow + quad * 8);
            bf16x8 pf1 = *(const bf16x8*)(prow + 32 + quad * 8);
#pragma unroll
            for (int dt = 0; dt < 4; dt++) {
                const int row = dt * 16 + col;
                bf16x8 vf0 = *(const bf16x8*)&Vc[row * 64 + cswz0 * 8];
                bf16x8 vf1 = *(const bf16x8*)&Vc[row * 64 + cswz1 * 8];
                o[mi][dt] = __builtin_amdgcn_mfma_f32_16x16x32_bf16(pf0, vf0, o[mi][dt], 0, 0, 0);
                o[mi][dt] = __builtin_amdgcn_mfma_f32_16x16x32_bf16(pf1, vf1, o[mi][dt], 0, 0, 0);
            }
        }
    }

    // final row-sum reduction over quads (partials partitioned by quad)
#pragma unroll
    for (int ni = 0; ni < 2; ni++) {
        rs[ni] += __shfl_xor(rs[ni], 16);
        rs[ni] += __shfl_xor(rs[ni], 32);
        if (quad == 0) L_lds[wave * 32 + ni * 16 + col] = rs[ni];
    }
    __syncthreads();
    f32x4 lf[2];
#pragma unroll
    for (int mi = 0; mi < 2; mi++)
        lf[mi] = *(const f32x4*)&L_lds[wave * 32 + mi * 16 + quad * 4];

    // epilogue: bf16 Ob[b][t][h*64+d]
#pragma unroll
    for (int mi = 0; mi < 2; mi++)
#pragma unroll
        for (int r = 0; r < 4; r++) {
            float inv = 1.f / lf[mi][r];
            int t = q0 + wave * 32 + mi * 16 + quad * 4 + r;
            unsigned short* orow = Ob + ((long)(b * SEQT + t)) * EMBED + h * HDIM;
#pragma unroll
            for (int dt = 0; dt < 4; dt++)
                orow[dt * 16 + col] = f2bf_hw(o[mi][dt][r] * inv);
        }
}

extern "C" void kernel_launch(void* const* d_in, const int* in_sizes, int n_in,
                              void* d_out, int out_size, void* d_ws, size_t ws_size,
                              hipStream_t stream)
{
    const float* x     = (const float*)d_in[0];
    const float* Wqkv  = (const float*)d_in[1];
    const float* bqkv  = (const float*)d_in[2];
    const float* Wproj = (const float*)d_in[3];
    const float* bproj = (const float*)d_in[4];
    float* out = (float*)d_out;

    const long Mbt = (long)BATCH * SEQT;                 // 8192
    const long per = (long)BATCH * NHEAD * SEQT * HDIM;  // 8,388,608 elems

    unsigned short* xb  = (unsigned short*)d_ws;
    unsigned short* wqb = xb  + per;
    unsigned short* wpb = wqb + 3 * EMBED * EMBED;
    unsigned short* Qb  = wpb + EMBED * EMBED;           // bf16 [bh][t][d], pre-scaled
    unsigned short* Kb  = Qb + per;
    unsigned short* Vt  = Kb + per;                      // bf16 [bh][d][t]
    unsigned short* Ob  = Vt + per;                      // bf16 [B,T,C]

    cvt_all<<<12288, 256, 0, stream>>>(x, Wqkv, Wproj, xb, wqb, wpb);

    dim3 g1(3 * EMBED / 128, Mbt / 256);                 // 24 x 32 = 768 blocks
    gemm_bt_pipe<1><<<g1, 512, 0, stream>>>(xb, wqb, bqkv, Qb, Kb, Vt,
                                            (int)Mbt, 3 * EMBED);

    flash_attn_mfma4<<<1024, 256, 0, stream>>>(Qb, Kb, Vt, Ob);

    dim3 g3(EMBED / 128, Mbt / 256);                     // 8 x 32 = 256 blocks
    gemm_bt_pipe<0><<<g3, 512, 0, stream>>>(Ob, wpb, bproj, out, nullptr, nullptr,
                                            (int)Mbt, EMBED);
}